// Round 5
// baseline (504.844 us; speedup 1.0000x reference)
//
#include <hip/hip_runtime.h>
#include <hip/hip_bf16.h>

#define N_NODES 50000
#define N_EDGES 800000
// HEADS=4, OUT_CH=64, F=256 hard-coded. All harness I/O float32.
// Internal H layout INTERLEAVED: H[node*256 + c*4 + h]  (c=channel 0..63, h=head 0..3)

typedef __attribute__((ext_vector_type(8))) short short8;   // 8 bf16 = 4 VGPRs (MFMA A/B frag)
typedef __attribute__((ext_vector_type(4))) float floatx4;  // MFMA C/D frag
typedef __attribute__((ext_vector_type(2))) uint uintx2;

__device__ __forceinline__ ushort f2bf(float f) {           // RNE f32->bf16 bits
    uint u = __float_as_uint(f);
    uint r = u + 0x7FFFu + ((u >> 16) & 1u);
    return (ushort)(r >> 16);
}
__device__ __forceinline__ float bfu2f(ushort h) {
    return __uint_as_float(((uint)h) << 16);
}
__device__ __forceinline__ float bflo(uint u) { return __uint_as_float(u << 16); }
__device__ __forceinline__ float bfhi(uint u) { return __uint_as_float(u & 0xffff0000u); }
__device__ __forceinline__ float lrelu(float e) { return e >= 0.f ? e : 0.2f * e; }

// ---------------- CSR build (dst-sorted incoming edge lists) ----------------
__global__ void deg_kernel(const int* __restrict__ dst, int* __restrict__ cnt, int E) {
    int i = blockIdx.x * blockDim.x + threadIdx.x;
    if (i < E) atomicAdd(&cnt[dst[i]], 1);
}

__global__ __launch_bounds__(256) void scan1_kernel(const int* __restrict__ cnt,
                                                    int* __restrict__ excl,
                                                    int* __restrict__ partial, int n) {
    __shared__ int sd[256];
    int tid = threadIdx.x;
    int i = blockIdx.x * 256 + tid;
    int v = (i < n) ? cnt[i] : 0;
    sd[tid] = v;
    __syncthreads();
    #pragma unroll
    for (int off = 1; off < 256; off <<= 1) {
        int t = (tid >= off) ? sd[tid - off] : 0;
        __syncthreads();
        sd[tid] += t;
        __syncthreads();
    }
    if (i < n) excl[i] = sd[tid] - v;
    if (tid == 255) partial[blockIdx.x] = sd[255];
}

__global__ __launch_bounds__(256) void scan2_kernel(int* __restrict__ partial, int nb) {
    __shared__ int sd[256];
    int tid = threadIdx.x;
    int v = (tid < nb) ? partial[tid] : 0;
    sd[tid] = v;
    __syncthreads();
    #pragma unroll
    for (int off = 1; off < 256; off <<= 1) {
        int t = (tid >= off) ? sd[tid - off] : 0;
        __syncthreads();
        sd[tid] += t;
        __syncthreads();
    }
    if (tid < nb) partial[tid] = sd[tid] - v;   // exclusive
}

__global__ __launch_bounds__(256) void scan3_kernel(const int* __restrict__ excl,
                                                    const int* __restrict__ partial,
                                                    int* __restrict__ row_ptr,
                                                    int* __restrict__ row_tmp, int n) {
    int i = blockIdx.x * 256 + threadIdx.x;
    if (i < n) {
        int v = excl[i] + partial[blockIdx.x];
        row_ptr[i] = v;
        row_tmp[i] = v;
    }
    if (i == 0) row_ptr[n] = N_EDGES;
}

__global__ void scatter_kernel(const int* __restrict__ src, const int* __restrict__ dst,
                               int* __restrict__ row_tmp, int* __restrict__ sorted_src,
                               int* __restrict__ sorted_dst, int E) {
    int i = blockIdx.x * blockDim.x + threadIdx.x;
    if (i < E) {
        int d = dst[i];
        int p = atomicAdd(&row_tmp[d], 1);
        sorted_src[p] = src[i];
        sorted_dst[p] = d;
    }
}

// ------ W prep: transpose + bf16 hi/lo split + fused att columns -----------
// Wt layout: 272 rows x 256 k. Rows 0-255: W^T. Rows 256+h: v_s[:,h] = W @ att_s
// head h (f32 dot, then hi/lo split). Rows 260+h: v_d. Rows 264-271: zero.
// This folds the attention-logit computation into the GEMM as 8 extra columns:
// a_src = (A W) att_s = A (W att_s)  -- bilinear identity, f32 v precompute.
__global__ __launch_bounds__(320) void prep_w(const float* __restrict__ W1,
                                              const float* __restrict__ W2,
                                              const float* __restrict__ as1,
                                              const float* __restrict__ ad1,
                                              const float* __restrict__ as2,
                                              const float* __restrict__ ad2,
                                              ushort* __restrict__ Wt1_hi,
                                              ushort* __restrict__ Wt1_lo,
                                              ushort* __restrict__ Wt2_hi,
                                              ushort* __restrict__ Wt2_lo) {
    int t = threadIdx.x, k = blockIdx.x & 255;
    int l1 = (blockIdx.x < 256);
    const float* W = l1 ? W1 : W2;
    const float* as_ = l1 ? as1 : as2;
    const float* ad_ = l1 ? ad1 : ad2;
    ushort* Wh = l1 ? Wt1_hi : Wt2_hi;
    ushort* Wl = l1 ? Wt1_lo : Wt2_lo;
    if (t < 256) {
        float v = W[k * 256 + t];
        ushort hb = f2bf(v);
        Wh[t * 256 + k] = hb;
        Wl[t * 256 + k] = f2bf(v - bfu2f(hb));
    } else if (t < 264) {
        int j = t - 256;                 // 0-3: att_src head j; 4-7: att_dst head j-4
        int h = j & 3;
        const float* vec = (j < 4) ? as_ : ad_;
        float acc = 0.f;
        for (int c = 0; c < 64; c++) acc += W[k * 256 + h * 64 + c] * vec[h * 64 + c];
        ushort hb = f2bf(acc);
        Wh[t * 256 + k] = hb;            // row 256+j
        Wl[t * 256 + k] = f2bf(acc - bfu2f(hb));
    } else if (t < 272) {
        Wh[t * 256 + k] = 0;             // rows 264-271: zero pad
        Wl[t * 256 + k] = 0;
    }
}

// ------- GEMM + attention logits: NO LDS, NO BARRIERS, occupancy-first -------
// Block: 32 rows x 272 cols, 4 waves. Wave w owns channel-chunk [16w,16w+16)
// for ALL 4 heads: tiles {w, w+4, w+8, w+12} x 2 row-groups. B read straight
// from global (W ~278 KB, L2-resident, 16B/lane coalesced). Col 256+l16 =
// fused att columns (wave 0 only) -> accA IS a_src/a_dst, no shuffles.
// Per-wave state ~150 regs -> __launch_bounds__(256,3): 3 waves/SIMD resident,
// free-running (zero barriers); A+B both prefetched one k-step ahead.
__global__ __launch_bounds__(256, 3) void gemm_att_kernel(const float* __restrict__ A,
                                                          const ushort* __restrict__ Wt_hi,
                                                          const ushort* __restrict__ Wt_lo,
                                                          ushort* __restrict__ H,
                                                          float* __restrict__ a_src,
                                                          float* __restrict__ a_dst, int M) {
    const int tid = threadIdx.x;
    const int wave = tid >> 6, lane = tid & 63;
    const int quad = lane >> 4, l16 = lane & 15;
    const int brow = blockIdx.x * 32;

    floatx4 acc[2][4];                   // [row-group][tile]; col = wave*16+tile*64+l16
    floatx4 accA[2];                     // att tile (wave 0): col = 256+l16
    #pragma unroll
    for (int rg = 0; rg < 2; rg++) {
        accA[rg] = (floatx4){0.f, 0.f, 0.f, 0.f};
        #pragma unroll
        for (int i = 0; i < 4; i++) acc[rg][i] = (floatx4){0.f, 0.f, 0.f, 0.f};
    }

    int ar[2];                           // clamped A rows per row-group
    #pragma unroll
    for (int rg = 0; rg < 2; rg++) {
        int r = brow + rg * 16 + l16;
        ar[rg] = (r < M) ? r : (M - 1);
    }
    const size_t bofs = (size_t)(wave * 16 + l16) * 256 + quad * 8;
    const ushort* bh0 = Wt_hi + bofs;    // + tile*64*256 + k0
    const ushort* bl0 = Wt_lo + bofs;
    const ushort* bha0 = Wt_hi + (size_t)(256 + l16) * 256 + quad * 8;
    const ushort* bla0 = Wt_lo + (size_t)(256 + l16) * 256 + quad * 8;

    short8 bh[4], bl[4], bhn[4], bln[4];
    float4 af0[2], af1[2];

    // prologue: B(0), A(0)
    #pragma unroll
    for (int i = 0; i < 4; i++) {
        bh[i] = *reinterpret_cast<const short8*>(bh0 + i * 64 * 256);
        bl[i] = *reinterpret_cast<const short8*>(bl0 + i * 64 * 256);
    }
    #pragma unroll
    for (int rg = 0; rg < 2; rg++) {
        const float* ap = A + (size_t)ar[rg] * 256 + quad * 8;
        af0[rg] = *reinterpret_cast<const float4*>(ap);
        af1[rg] = *reinterpret_cast<const float4*>(ap + 4);
    }

    #pragma unroll
    for (int t = 0; t < 8; t++) {
        const int k0 = t * 32;
        if (t < 7) {                     // prefetch B(t+1)
            #pragma unroll
            for (int i = 0; i < 4; i++) {
                bhn[i] = *reinterpret_cast<const short8*>(bh0 + i * 64 * 256 + k0 + 32);
                bln[i] = *reinterpret_cast<const short8*>(bl0 + i * 64 * 256 + k0 + 32);
            }
        }
        short8 bha, bla;
        if (wave == 0) {                 // att B columns, L2-hot (wave-uniform branch)
            bha = *reinterpret_cast<const short8*>(bha0 + k0);
            bla = *reinterpret_cast<const short8*>(bla0 + k0);
        }
        // convert A(t) -> bf16 hi/lo
        short8 ah[2], al[2];
        #pragma unroll
        for (int rg = 0; rg < 2; rg++) {
            float av[8] = {af0[rg].x, af0[rg].y, af0[rg].z, af0[rg].w,
                           af1[rg].x, af1[rg].y, af1[rg].z, af1[rg].w};
            #pragma unroll
            for (int j = 0; j < 8; j++) {
                ushort hb = f2bf(av[j]);
                ah[rg][j] = (short)hb;
                al[rg][j] = (short)f2bf(av[j] - bfu2f(hb));
            }
        }
        if (t < 7) {                     // prefetch A(t+1) into freed af regs
            #pragma unroll
            for (int rg = 0; rg < 2; rg++) {
                const float* ap = A + (size_t)ar[rg] * 256 + quad * 8 + k0 + 32;
                af0[rg] = *reinterpret_cast<const float4*>(ap);
                af1[rg] = *reinterpret_cast<const float4*>(ap + 4);
            }
        }
        #pragma unroll
        for (int rg = 0; rg < 2; rg++) {
            #pragma unroll
            for (int i = 0; i < 4; i++) {
                acc[rg][i] = __builtin_amdgcn_mfma_f32_16x16x32_bf16(ah[rg], bh[i], acc[rg][i], 0, 0, 0);
                acc[rg][i] = __builtin_amdgcn_mfma_f32_16x16x32_bf16(ah[rg], bl[i], acc[rg][i], 0, 0, 0);
                acc[rg][i] = __builtin_amdgcn_mfma_f32_16x16x32_bf16(al[rg], bh[i], acc[rg][i], 0, 0, 0);
            }
        }
        if (wave == 0) {
            #pragma unroll
            for (int rg = 0; rg < 2; rg++) {
                accA[rg] = __builtin_amdgcn_mfma_f32_16x16x32_bf16(ah[rg], bha, accA[rg], 0, 0, 0);
                accA[rg] = __builtin_amdgcn_mfma_f32_16x16x32_bf16(ah[rg], bla, accA[rg], 0, 0, 0);
                accA[rg] = __builtin_amdgcn_mfma_f32_16x16x32_bf16(al[rg], bha, accA[rg], 0, 0, 0);
            }
        }
        #pragma unroll
        for (int i = 0; i < 4; i++) { bh[i] = bhn[i]; bl[i] = bln[i]; }
    }
    // epilogue: packed H store (4 heads per lane) + att store (wave 0, l16<8)
    #pragma unroll
    for (int rg = 0; rg < 2; rg++) {
        #pragma unroll
        for (int r = 0; r < 4; r++) {
            int m = brow + rg * 16 + quad * 4 + r;
            if (m < M) {
                uintx2 pk;
                pk.x = (uint)f2bf(acc[rg][0][r]) | ((uint)f2bf(acc[rg][1][r]) << 16);
                pk.y = (uint)f2bf(acc[rg][2][r]) | ((uint)f2bf(acc[rg][3][r]) << 16);
                *reinterpret_cast<uintx2*>(H + (size_t)m * 256 + (wave * 16 + l16) * 4) = pk;
                if (wave == 0) {
                    float v = accA[rg][r];
                    if (l16 < 4) a_src[m * 4 + l16] = v;
                    else if (l16 < 8) a_dst[m * 4 + (l16 - 4)] = v;
                }
            }
        }
    }
}

// ---------------- edge weights: w = exp(lrelu(a_src[s]+a_dst[d])) -----------
// No max-subtraction: logits bounded (|e| ~ O(10)), f32 exp safe; alpha = w/sum(w)
// is mathematically identical to the max-subtracted form.
__global__ __launch_bounds__(256) void ew_kernel(const float* __restrict__ a_src,
                                                 const float* __restrict__ a_dst,
                                                 const int* __restrict__ sorted_src,
                                                 const int* __restrict__ sorted_dst,
                                                 float* __restrict__ ew, int E) {
    int j = blockIdx.x * 256 + threadIdx.x;
    if (j >= E) return;
    int s = sorted_src[j], d = sorted_dst[j];
    float4 as_ = *reinterpret_cast<const float4*>(a_src + (size_t)s * 4);
    float4 ad_ = *reinterpret_cast<const float4*>(a_dst + (size_t)d * 4);
    float4 w;
    w.x = __expf(lrelu(as_.x + ad_.x));
    w.y = __expf(lrelu(as_.y + ad_.y));
    w.z = __expf(lrelu(as_.z + ad_.z));
    w.w = __expf(lrelu(as_.w + ad_.w));
    *reinterpret_cast<float4*>(ew + (size_t)j * 4) = w;
}

// ---------------- weighted gather, one wave per node ------------------------
// All 64 lanes on ONE edge: lane = channel c, uint2 = heads 0..3 bf16.
// Node index forced wave-uniform via readfirstlane so the per-edge metadata
// (sorted_src, ew) compiles to scalar loads; 8 H-row gathers in flight.
// Tail groups over-read: memory-safe because sorted/sortedd and ew/a_src are
// exactly contiguous in the workspace (garbage indices are still valid node
// ids in [0,N)); invalid weights are skipped under a uniform branch.
// NOTE: macro params named W_/V_ to avoid the preprocessor substituting the
// parameter name inside swizzle members (.w).
#define AGG_ACC(W_, V_)                                                     \
    do {                                                                    \
        a0 += (W_).x * bflo((V_).x); a1 += (W_).y * bfhi((V_).x);           \
        a2 += (W_).z * bflo((V_).y); a3 += (W_).w * bfhi((V_).y);           \
        dp0 += (W_).x; dp1 += (W_).y; dp2 += (W_).z; dp3 += (W_).w;         \
    } while (0)

__global__ __launch_bounds__(256) void agg_kernel(const ushort* __restrict__ H,
                                                  const float* __restrict__ a_src,
                                                  const float* __restrict__ a_dst,
                                                  const int* __restrict__ row_ptr,
                                                  const int* __restrict__ sorted_src,
                                                  const float* __restrict__ ew,
                                                  const float* __restrict__ bias,
                                                  float* __restrict__ out, int N) {
    const int lane = threadIdx.x & 63;
    const int i = __builtin_amdgcn_readfirstlane(blockIdx.x * 4 + (threadIdx.x >> 6));
    if (i >= N) return;
    const float4 asv = *reinterpret_cast<const float4*>(a_src + (size_t)i * 4);
    const float4 adv = *reinterpret_cast<const float4*>(a_dst + (size_t)i * 4);
    const float ws0 = __expf(lrelu(asv.x + adv.x)), ws1 = __expf(lrelu(asv.y + adv.y));
    const float ws2 = __expf(lrelu(asv.z + adv.z)), ws3 = __expf(lrelu(asv.w + adv.w));
    const int start = row_ptr[i], end = row_ptr[i + 1];

    float a0 = 0.f, a1 = 0.f, a2 = 0.f, a3 = 0.f;
    float dp0 = 0.f, dp1 = 0.f, dp2 = 0.f, dp3 = 0.f;
    const ushort* __restrict__ Hl = H + lane * 4;   // this lane's channel slice

    for (int j0 = start; j0 < end; j0 += 8) {
        int s[8];
        #pragma unroll
        for (int k = 0; k < 8; k++) s[k] = sorted_src[j0 + k];        // s_load_dwordx8
        floatx4 w[8];
        #pragma unroll
        for (int k = 0; k < 8; k++)                                   // 2x s_load_dwordx16
            w[k] = *reinterpret_cast<const floatx4*>(ew + (size_t)(j0 + k) * 4);
        uintx2 hv[8];
        #pragma unroll
        for (int k = 0; k < 8; k++)                                   // 8 gathers in flight
            hv[k] = *reinterpret_cast<const uintx2*>(Hl + (size_t)s[k] * 256);
        if (j0 + 8 <= end) {
            #pragma unroll
            for (int k = 0; k < 8; k++) AGG_ACC(w[k], hv[k]);
        } else {
            #pragma unroll
            for (int k = 0; k < 8; k++)
                if (j0 + k < end) AGG_ACC(w[k], hv[k]);               // uniform branch
        }
    }
    // self loop
    {
        uintx2 hv = *reinterpret_cast<const uintx2*>(Hl + (size_t)i * 256);
        a0 += ws0 * bflo(hv.x); a1 += ws1 * bfhi(hv.x);
        a2 += ws2 * bflo(hv.y); a3 += ws3 * bfhi(hv.y);
    }
    const float r0 = 1.f / (dp0 + ws0 + 1e-16f), r1 = 1.f / (dp1 + ws1 + 1e-16f);
    const float r2 = 1.f / (dp2 + ws2 + 1e-16f), r3 = 1.f / (dp3 + ws3 + 1e-16f);
    // out[i*256 + h*64 + c], c = lane; nontemporal: don't evict H from L2
    float* op = out + (size_t)i * 256 + lane;
    float v;
    v = a0 * r0 + bias[lane];        v = (v > 0.f) ? v : expm1f(v);
    __builtin_nontemporal_store(v, op);
    v = a1 * r1 + bias[64 + lane];   v = (v > 0.f) ? v : expm1f(v);
    __builtin_nontemporal_store(v, op + 64);
    v = a2 * r2 + bias[128 + lane];  v = (v > 0.f) ? v : expm1f(v);
    __builtin_nontemporal_store(v, op + 128);
    v = a3 * r3 + bias[192 + lane];  v = (v > 0.f) ? v : expm1f(v);
    __builtin_nontemporal_store(v, op + 192);
}

extern "C" void kernel_launch(void* const* d_in, const int* in_sizes, int n_in,
                              void* d_out, int out_size, void* d_ws, size_t ws_size,
                              hipStream_t stream) {
    const float* x      = (const float*)d_in[0];
    const int*   eidx   = (const int*)d_in[1];
    const float* W1     = (const float*)d_in[2];
    const float* att_s1 = (const float*)d_in[3];
    const float* att_d1 = (const float*)d_in[4];
    const float* b1     = (const float*)d_in[5];
    const float* W2     = (const float*)d_in[6];
    const float* att_s2 = (const float*)d_in[7];
    const float* att_d2 = (const float*)d_in[8];
    const float* b2     = (const float*)d_in[9];
    float* out = (float*)d_out;

    const int N = N_NODES, E = N_EDGES;
    char* ws = (char*)d_ws;
    size_t off = 0;
    auto alloc = [&](size_t bytes) -> void* {
        void* p = ws + off;
        off += (bytes + 255) & ~(size_t)255;
        return p;
    };
    // total ws ~ 48 MB (proven-good envelope: 57 MB)
    // NOTE: agg_kernel's tail over-read relies on (ew -> a_src) and
    // (sorted -> sortedd) being contiguous: E*16 and E*4 are 256-aligned.
    ushort* h       = (ushort*)alloc((size_t)N * 256 * sizeof(ushort));  // 25.6 MB
    float*  ew      = (float*) alloc((size_t)E * 4 * sizeof(float));     // 12.8 MB
    float*  a_src   = (float*) alloc((size_t)N * 4 * sizeof(float));
    float*  a_dst   = (float*) alloc((size_t)N * 4 * sizeof(float));
    int*    cnt     = (int*)   alloc((size_t)N * sizeof(int));
    int*    row_ptr = (int*)   alloc((size_t)(N + 1) * sizeof(int));
    int*    row_tmp = (int*)   alloc((size_t)N * sizeof(int));
    int*    sorted  = (int*)   alloc((size_t)E * sizeof(int));
    int*    sortedd = (int*)   alloc((size_t)E * sizeof(int));
    int*    excl    = (int*)   alloc((size_t)N * sizeof(int));
    int*    partial = (int*)   alloc(256 * sizeof(int));
    ushort* Wt1_hi  = (ushort*)alloc(272 * 256 * sizeof(ushort));   // 256 W^T + 8 att + 8 zero
    ushort* Wt1_lo  = (ushort*)alloc(272 * 256 * sizeof(ushort));
    ushort* Wt2_hi  = (ushort*)alloc(272 * 256 * sizeof(ushort));
    ushort* Wt2_lo  = (ushort*)alloc(272 * 256 * sizeof(ushort));
    float*  x2      = out;   // layer-1 f32 activations live in d_out, overwritten by layer 2
    (void)ws_size; (void)in_sizes; (void)n_in; (void)out_size;

    const int* e_src = eidx;
    const int* e_dst = eidx + E;
    const int nsb = (N + 255) / 256;   // 196 scan blocks
    const int neb = (E + 255) / 256;

    prep_w<<<512, 320, 0, stream>>>(W1, W2, att_s1, att_d1, att_s2, att_d2,
                                    Wt1_hi, Wt1_lo, Wt2_hi, Wt2_lo);
    hipMemsetAsync(cnt, 0, N * sizeof(int), stream);
    deg_kernel<<<neb, 256, 0, stream>>>(e_dst, cnt, E);
    scan1_kernel<<<nsb, 256, 0, stream>>>(cnt, excl, partial, N);
    scan2_kernel<<<1, 256, 0, stream>>>(partial, nsb);
    scan3_kernel<<<nsb, 256, 0, stream>>>(excl, partial, row_ptr, row_tmp, N);
    scatter_kernel<<<neb, 256, 0, stream>>>(e_src, e_dst, row_tmp, sorted, sortedd, E);

    int ggrid = (N + 31) / 32;     // 1563 blocks (32 rows each)
    int nblk = (N + 3) / 4;        // 12500
    // layer 1
    gemm_att_kernel<<<ggrid, 256, 0, stream>>>(x, Wt1_hi, Wt1_lo, h, a_src, a_dst, N);
    ew_kernel<<<neb, 256, 0, stream>>>(a_src, a_dst, sorted, sortedd, ew, E);
    agg_kernel<<<nblk, 256, 0, stream>>>(h, a_src, a_dst, row_ptr, sorted, ew, b1, x2, N);
    // layer 2
    gemm_att_kernel<<<ggrid, 256, 0, stream>>>(x2, Wt2_hi, Wt2_lo, h, a_src, a_dst, N);
    ew_kernel<<<neb, 256, 0, stream>>>(a_src, a_dst, sorted, sortedd, ew, E);
    agg_kernel<<<nblk, 256, 0, stream>>>(h, a_src, a_dst, row_ptr, sorted, ew, b2, out, N);
}

// Round 7
// 458.654 us; speedup vs baseline: 1.1007x; 1.1007x over previous
//
#include <hip/hip_runtime.h>
#include <hip/hip_bf16.h>

#define N_NODES 50000
#define N_EDGES 800000
// HEADS=4, OUT_CH=64, F=256 hard-coded. All harness I/O float32.
// Internal H layout INTERLEAVED: H[node*256 + c*4 + h]  (c=channel 0..63, h=head 0..3)

typedef __attribute__((ext_vector_type(8))) short short8;   // 8 bf16 = 4 VGPRs (MFMA A/B frag)
typedef __attribute__((ext_vector_type(4))) float floatx4;  // MFMA C/D frag
typedef __attribute__((ext_vector_type(2))) uint uintx2;

__device__ __forceinline__ ushort f2bf(float f) {           // RNE f32->bf16 bits
    uint u = __float_as_uint(f);
    uint r = u + 0x7FFFu + ((u >> 16) & 1u);
    return (ushort)(r >> 16);
}
__device__ __forceinline__ float bfu2f(ushort h) {
    return __uint_as_float(((uint)h) << 16);
}
__device__ __forceinline__ float bflo(uint u) { return __uint_as_float(u << 16); }
__device__ __forceinline__ float bfhi(uint u) { return __uint_as_float(u & 0xffff0000u); }
__device__ __forceinline__ float lrelu(float e) { return e >= 0.f ? e : 0.2f * e; }

// ---------------- CSR build (dst-sorted incoming edge lists) ----------------
__global__ void deg_kernel(const int* __restrict__ dst, int* __restrict__ cnt, int E) {
    int i = blockIdx.x * blockDim.x + threadIdx.x;
    if (i < E) atomicAdd(&cnt[dst[i]], 1);
}

__global__ __launch_bounds__(256) void scan1_kernel(const int* __restrict__ cnt,
                                                    int* __restrict__ excl,
                                                    int* __restrict__ partial, int n) {
    __shared__ int sd[256];
    int tid = threadIdx.x;
    int i = blockIdx.x * 256 + tid;
    int v = (i < n) ? cnt[i] : 0;
    sd[tid] = v;
    __syncthreads();
    #pragma unroll
    for (int off = 1; off < 256; off <<= 1) {
        int t = (tid >= off) ? sd[tid - off] : 0;
        __syncthreads();
        sd[tid] += t;
        __syncthreads();
    }
    if (i < n) excl[i] = sd[tid] - v;
    if (tid == 255) partial[blockIdx.x] = sd[255];
}

__global__ __launch_bounds__(256) void scan2_kernel(int* __restrict__ partial, int nb) {
    __shared__ int sd[256];
    int tid = threadIdx.x;
    int v = (tid < nb) ? partial[tid] : 0;
    sd[tid] = v;
    __syncthreads();
    #pragma unroll
    for (int off = 1; off < 256; off <<= 1) {
        int t = (tid >= off) ? sd[tid - off] : 0;
        __syncthreads();
        sd[tid] += t;
        __syncthreads();
    }
    if (tid < nb) partial[tid] = sd[tid] - v;   // exclusive
}

__global__ __launch_bounds__(256) void scan3_kernel(const int* __restrict__ excl,
                                                    const int* __restrict__ partial,
                                                    int* __restrict__ row_ptr,
                                                    int* __restrict__ row_tmp, int n) {
    int i = blockIdx.x * 256 + threadIdx.x;
    if (i < n) {
        int v = excl[i] + partial[blockIdx.x];
        row_ptr[i] = v;
        row_tmp[i] = v;
    }
    if (i == 0) row_ptr[n] = N_EDGES;
}

__global__ void scatter_kernel(const int* __restrict__ src, const int* __restrict__ dst,
                               int* __restrict__ row_tmp, int* __restrict__ sorted_src,
                               int* __restrict__ sorted_dst, int E) {
    int i = blockIdx.x * blockDim.x + threadIdx.x;
    if (i < E) {
        int d = dst[i];
        int p = atomicAdd(&row_tmp[d], 1);
        sorted_src[p] = src[i];
        sorted_dst[p] = d;
    }
}

// ------ W prep: transpose + bf16 hi/lo split (+ unused fused att rows) ------
__global__ __launch_bounds__(320) void prep_w(const float* __restrict__ W1,
                                              const float* __restrict__ W2,
                                              const float* __restrict__ as1,
                                              const float* __restrict__ ad1,
                                              const float* __restrict__ as2,
                                              const float* __restrict__ ad2,
                                              ushort* __restrict__ Wt1_hi,
                                              ushort* __restrict__ Wt1_lo,
                                              ushort* __restrict__ Wt2_hi,
                                              ushort* __restrict__ Wt2_lo) {
    int t = threadIdx.x, k = blockIdx.x & 255;
    int l1 = (blockIdx.x < 256);
    const float* W = l1 ? W1 : W2;
    const float* as_ = l1 ? as1 : as2;
    const float* ad_ = l1 ? ad1 : ad2;
    ushort* Wh = l1 ? Wt1_hi : Wt2_hi;
    ushort* Wl = l1 ? Wt1_lo : Wt2_lo;
    if (t < 256) {
        float v = W[k * 256 + t];
        ushort hb = f2bf(v);
        Wh[t * 256 + k] = hb;
        Wl[t * 256 + k] = f2bf(v - bfu2f(hb));
    } else if (t < 264) {
        int j = t - 256;
        int h = j & 3;
        const float* vec = (j < 4) ? as_ : ad_;
        float acc = 0.f;
        for (int c = 0; c < 64; c++) acc += W[k * 256 + h * 64 + c] * vec[h * 64 + c];
        ushort hb = f2bf(acc);
        Wh[t * 256 + k] = hb;
        Wl[t * 256 + k] = f2bf(acc - bfu2f(hb));
    } else if (t < 272) {
        Wh[t * 256 + k] = 0;
        Wl[t * 256 + k] = 0;
    }
}

// ------- GEMM + fused attention logits, col-split (R2-proven structure) -----
// Block: 64 rows x 128 cols; blockIdx.y=0 -> cols 0..127 (heads 0,1),
// blockIdx.y=1 -> cols 128..255 (heads 2,3). bf16x3 split MFMA.
// Sole change vs R2: packed head-pair H store (uint instead of 2x ushort).
__global__ __launch_bounds__(256) void gemm_att_kernel(const float* __restrict__ A,
                                                       const ushort* __restrict__ Wt_hi,
                                                       const ushort* __restrict__ Wt_lo,
                                                       const float* __restrict__ att_s,
                                                       const float* __restrict__ att_d,
                                                       ushort* __restrict__ H,
                                                       float* __restrict__ a_src,
                                                       float* __restrict__ a_dst, int M) {
    const int ROWP = 40;
    __shared__ ushort hi_s[128 * ROWP];   // 10 KB
    __shared__ ushort lo_s[128 * ROWP];   // 10 KB
    const int tid = threadIdx.x;
    const int wave = tid >> 6, lane = tid & 63;
    const int quad = lane >> 4, l16 = lane & 15;
    const int brow = blockIdx.x * 64;
    const int coff = blockIdx.y * 128;    // column offset (also Wt row offset)
    const int mrow = brow + wave * 16 + l16;
    const int mload = (mrow < M) ? mrow : (M - 1);

    floatx4 acc[8];
    #pragma unroll
    for (int t = 0; t < 8; t++) acc[t] = (floatx4){0.f, 0.f, 0.f, 0.f};

    for (int k0 = 0; k0 < 256; k0 += 32) {
        __syncthreads();
        {   // stage 128 cols x 32 k: threads 0-127 stage hi, 128-255 stage lo
            int t = tid & 127;
            const ushort* g = ((tid < 128) ? Wt_hi : Wt_lo) + (size_t)(coff + t) * 256 + k0;
            ushort* d = ((tid < 128) ? hi_s : lo_s) + t * ROWP;
            #pragma unroll
            for (int i = 0; i < 4; i++)
                *reinterpret_cast<short8*>(d + i * 8) =
                    *reinterpret_cast<const short8*>(g + i * 8);
        }
        __syncthreads();
        const float* ap = A + (size_t)mload * 256 + k0 + quad * 8;
        float4 a0 = *reinterpret_cast<const float4*>(ap);
        float4 a1 = *reinterpret_cast<const float4*>(ap + 4);
        float av[8] = {a0.x, a0.y, a0.z, a0.w, a1.x, a1.y, a1.z, a1.w};
        short8 a_hi, a_lo;
        #pragma unroll
        for (int j = 0; j < 8; j++) {
            ushort hb = f2bf(av[j]);
            a_hi[j] = (short)hb;
            a_lo[j] = (short)f2bf(av[j] - bfu2f(hb));
        }
        #pragma unroll
        for (int t = 0; t < 8; t++) {
            int roff = (t * 16 + l16) * ROWP + quad * 8;
            short8 b_hi = *reinterpret_cast<const short8*>(&hi_s[roff]);
            short8 b_lo = *reinterpret_cast<const short8*>(&lo_s[roff]);
            acc[t] = __builtin_amdgcn_mfma_f32_16x16x32_bf16(a_hi, b_hi, acc[t], 0, 0, 0);
            acc[t] = __builtin_amdgcn_mfma_f32_16x16x32_bf16(a_hi, b_lo, acc[t], 0, 0, 0);
            acc[t] = __builtin_amdgcn_mfma_f32_16x16x32_bf16(a_lo, b_hi, acc[t], 0, 0, 0);
        }
    }
    // fused attention-logit partials: tiles 0-3 -> head coff/64, 4-7 -> +1
    const int hb = blockIdx.y * 2;
    float ps[2][4] = {}, pd[2][4] = {};
    #pragma unroll
    for (int t = 0; t < 8; t++) {
        int hh = t >> 2;
        float as_v = att_s[coff + t * 16 + l16];
        float ad_v = att_d[coff + t * 16 + l16];
        #pragma unroll
        for (int r = 0; r < 4; r++) {
            ps[hh][r] += acc[t][r] * as_v;
            pd[hh][r] += acc[t][r] * ad_v;
        }
    }
    #pragma unroll
    for (int off = 1; off < 16; off <<= 1) {
        #pragma unroll
        for (int hh = 0; hh < 2; hh++)
            #pragma unroll
            for (int r = 0; r < 4; r++) {
                ps[hh][r] += __shfl_xor(ps[hh][r], off, 64);
                pd[hh][r] += __shfl_xor(pd[hh][r], off, 64);
            }
    }
    if (l16 == 0) {
        #pragma unroll
        for (int r = 0; r < 4; r++) {
            int m = brow + wave * 16 + quad * 4 + r;
            if (m < M) {
                #pragma unroll
                for (int hh = 0; hh < 2; hh++) {
                    a_src[m * 4 + hb + hh] = ps[hh][r];
                    a_dst[m * 4 + hb + hh] = pd[hh][r];
                }
            }
        }
    }
    // store bf16 H, interleaved (c*4 + h), packed head-pairs: tiles t and t+4
    // share c = t*16 + l16 and hold heads hb, hb+1 -> one uint store.
    #pragma unroll
    for (int t = 0; t < 4; t++) {
        int c = t * 16 + l16;
        #pragma unroll
        for (int r = 0; r < 4; r++) {
            int m = brow + wave * 16 + quad * 4 + r;
            if (m < M) {
                uint pk = (uint)f2bf(acc[t][r]) | ((uint)f2bf(acc[t + 4][r]) << 16);
                *reinterpret_cast<uint*>(H + (size_t)m * 256 + c * 4 + hb) = pk;
            }
        }
    }
}

// ---------------- edge weights: w = exp(lrelu(a_src[s]+a_dst[d])) -----------
// No max-subtraction: logits bounded (|e| ~ O(10)), f32 exp safe; alpha = w/sum(w)
// is mathematically identical to the max-subtracted form.
__global__ __launch_bounds__(256) void ew_kernel(const float* __restrict__ a_src,
                                                 const float* __restrict__ a_dst,
                                                 const int* __restrict__ sorted_src,
                                                 const int* __restrict__ sorted_dst,
                                                 float* __restrict__ ew, int E) {
    int j = blockIdx.x * 256 + threadIdx.x;
    if (j >= E) return;
    int s = sorted_src[j], d = sorted_dst[j];
    float4 as_ = *reinterpret_cast<const float4*>(a_src + (size_t)s * 4);
    float4 ad_ = *reinterpret_cast<const float4*>(a_dst + (size_t)d * 4);
    float4 w;
    w.x = __expf(lrelu(as_.x + ad_.x));
    w.y = __expf(lrelu(as_.y + ad_.y));
    w.z = __expf(lrelu(as_.z + ad_.z));
    w.w = __expf(lrelu(as_.w + ad_.w));
    *reinterpret_cast<float4*>(ew + (size_t)j * 4) = w;
}

// ---------------- weighted gather, one wave per node ------------------------
// All 64 lanes on ONE edge: lane = channel c, uint2 = heads 0..3 bf16.
// Node index forced wave-uniform via readfirstlane so the per-edge metadata
// (sorted_src, ew) compiles to scalar loads; 8 H-row gathers in flight.
// Tail groups over-read: memory-safe because sorted/sortedd and ew/a_src are
// exactly contiguous in the workspace (garbage indices are still valid node
// ids in [0,N)); invalid weights are skipped under a uniform branch.
// NOTE: macro params named W_/V_ to avoid the preprocessor substituting the
// parameter name inside swizzle members (.w).
#define AGG_ACC(W_, V_)                                                     \
    do {                                                                    \
        a0 += (W_).x * bflo((V_).x); a1 += (W_).y * bfhi((V_).x);           \
        a2 += (W_).z * bflo((V_).y); a3 += (W_).w * bfhi((V_).y);           \
        dp0 += (W_).x; dp1 += (W_).y; dp2 += (W_).z; dp3 += (W_).w;         \
    } while (0)

__global__ __launch_bounds__(256) void agg_kernel(const ushort* __restrict__ H,
                                                  const float* __restrict__ a_src,
                                                  const float* __restrict__ a_dst,
                                                  const int* __restrict__ row_ptr,
                                                  const int* __restrict__ sorted_src,
                                                  const float* __restrict__ ew,
                                                  const float* __restrict__ bias,
                                                  float* __restrict__ out, int N) {
    const int lane = threadIdx.x & 63;
    const int i = __builtin_amdgcn_readfirstlane(blockIdx.x * 4 + (threadIdx.x >> 6));
    if (i >= N) return;
    const float4 asv = *reinterpret_cast<const float4*>(a_src + (size_t)i * 4);
    const float4 adv = *reinterpret_cast<const float4*>(a_dst + (size_t)i * 4);
    const float ws0 = __expf(lrelu(asv.x + adv.x)), ws1 = __expf(lrelu(asv.y + adv.y));
    const float ws2 = __expf(lrelu(asv.z + adv.z)), ws3 = __expf(lrelu(asv.w + adv.w));
    const int start = row_ptr[i], end = row_ptr[i + 1];

    float a0 = 0.f, a1 = 0.f, a2 = 0.f, a3 = 0.f;
    float dp0 = 0.f, dp1 = 0.f, dp2 = 0.f, dp3 = 0.f;
    const ushort* __restrict__ Hl = H + lane * 4;   // this lane's channel slice

    for (int j0 = start; j0 < end; j0 += 8) {
        int s[8];
        #pragma unroll
        for (int k = 0; k < 8; k++) s[k] = sorted_src[j0 + k];        // s_load_dwordx8
        floatx4 w[8];
        #pragma unroll
        for (int k = 0; k < 8; k++)                                   // 2x s_load_dwordx16
            w[k] = *reinterpret_cast<const floatx4*>(ew + (size_t)(j0 + k) * 4);
        uintx2 hv[8];
        #pragma unroll
        for (int k = 0; k < 8; k++)                                   // 8 gathers in flight
            hv[k] = *reinterpret_cast<const uintx2*>(Hl + (size_t)s[k] * 256);
        if (j0 + 8 <= end) {
            #pragma unroll
            for (int k = 0; k < 8; k++) AGG_ACC(w[k], hv[k]);
        } else {
            #pragma unroll
            for (int k = 0; k < 8; k++)
                if (j0 + k < end) AGG_ACC(w[k], hv[k]);               // uniform branch
        }
    }
    // self loop
    {
        uintx2 hv = *reinterpret_cast<const uintx2*>(Hl + (size_t)i * 256);
        a0 += ws0 * bflo(hv.x); a1 += ws1 * bfhi(hv.x);
        a2 += ws2 * bflo(hv.y); a3 += ws3 * bfhi(hv.y);
    }
    const float r0 = 1.f / (dp0 + ws0 + 1e-16f), r1 = 1.f / (dp1 + ws1 + 1e-16f);
    const float r2 = 1.f / (dp2 + ws2 + 1e-16f), r3 = 1.f / (dp3 + ws3 + 1e-16f);
    // out[i*256 + h*64 + c], c = lane; nontemporal: don't evict H from L2
    float* op = out + (size_t)i * 256 + lane;
    float v;
    v = a0 * r0 + bias[lane];        v = (v > 0.f) ? v : expm1f(v);
    __builtin_nontemporal_store(v, op);
    v = a1 * r1 + bias[64 + lane];   v = (v > 0.f) ? v : expm1f(v);
    __builtin_nontemporal_store(v, op + 64);
    v = a2 * r2 + bias[128 + lane];  v = (v > 0.f) ? v : expm1f(v);
    __builtin_nontemporal_store(v, op + 128);
    v = a3 * r3 + bias[192 + lane];  v = (v > 0.f) ? v : expm1f(v);
    __builtin_nontemporal_store(v, op + 192);
}

extern "C" void kernel_launch(void* const* d_in, const int* in_sizes, int n_in,
                              void* d_out, int out_size, void* d_ws, size_t ws_size,
                              hipStream_t stream) {
    const float* x      = (const float*)d_in[0];
    const int*   eidx   = (const int*)d_in[1];
    const float* W1     = (const float*)d_in[2];
    const float* att_s1 = (const float*)d_in[3];
    const float* att_d1 = (const float*)d_in[4];
    const float* b1     = (const float*)d_in[5];
    const float* W2     = (const float*)d_in[6];
    const float* att_s2 = (const float*)d_in[7];
    const float* att_d2 = (const float*)d_in[8];
    const float* b2     = (const float*)d_in[9];
    float* out = (float*)d_out;

    const int N = N_NODES, E = N_EDGES;
    char* ws = (char*)d_ws;
    size_t off = 0;
    auto alloc = [&](size_t bytes) -> void* {
        void* p = ws + off;
        off += (bytes + 255) & ~(size_t)255;
        return p;
    };
    // total ws ~ 48 MB (proven-good envelope: 57 MB)
    // NOTE: agg_kernel's tail over-read relies on (ew -> a_src) and
    // (sorted -> sortedd) being contiguous: E*16 and E*4 are 256-aligned.
    ushort* h       = (ushort*)alloc((size_t)N * 256 * sizeof(ushort));  // 25.6 MB
    float*  ew      = (float*) alloc((size_t)E * 4 * sizeof(float));     // 12.8 MB
    float*  a_src   = (float*) alloc((size_t)N * 4 * sizeof(float));
    float*  a_dst   = (float*) alloc((size_t)N * 4 * sizeof(float));
    int*    cnt     = (int*)   alloc((size_t)N * sizeof(int));
    int*    row_ptr = (int*)   alloc((size_t)(N + 1) * sizeof(int));
    int*    row_tmp = (int*)   alloc((size_t)N * sizeof(int));
    int*    sorted  = (int*)   alloc((size_t)E * sizeof(int));
    int*    sortedd = (int*)   alloc((size_t)E * sizeof(int));
    int*    excl    = (int*)   alloc((size_t)N * sizeof(int));
    int*    partial = (int*)   alloc(256 * sizeof(int));
    ushort* Wt1_hi  = (ushort*)alloc(272 * 256 * sizeof(ushort));   // 256 W^T + 8 att + 8 zero
    ushort* Wt1_lo  = (ushort*)alloc(272 * 256 * sizeof(ushort));
    ushort* Wt2_hi  = (ushort*)alloc(272 * 256 * sizeof(ushort));
    ushort* Wt2_lo  = (ushort*)alloc(272 * 256 * sizeof(ushort));
    float*  x2      = out;   // layer-1 f32 activations live in d_out, overwritten by layer 2
    (void)ws_size; (void)in_sizes; (void)n_in; (void)out_size;

    const int* e_src = eidx;
    const int* e_dst = eidx + E;
    const int nsb = (N + 255) / 256;   // 196 scan blocks
    const int neb = (E + 255) / 256;

    prep_w<<<512, 320, 0, stream>>>(W1, W2, att_s1, att_d1, att_s2, att_d2,
                                    Wt1_hi, Wt1_lo, Wt2_hi, Wt2_lo);
    hipMemsetAsync(cnt, 0, N * sizeof(int), stream);
    deg_kernel<<<neb, 256, 0, stream>>>(e_dst, cnt, E);
    scan1_kernel<<<nsb, 256, 0, stream>>>(cnt, excl, partial, N);
    scan2_kernel<<<1, 256, 0, stream>>>(partial, nsb);
    scan3_kernel<<<nsb, 256, 0, stream>>>(excl, partial, row_ptr, row_tmp, N);
    scatter_kernel<<<neb, 256, 0, stream>>>(e_src, e_dst, row_tmp, sorted, sortedd, E);

    dim3 ggrid((N + 63) / 64, 2);  // 782 x 2
    int nblk = (N + 3) / 4;        // 12500
    // layer 1
    gemm_att_kernel<<<ggrid, 256, 0, stream>>>(x, Wt1_hi, Wt1_lo, att_s1, att_d1,
                                               h, a_src, a_dst, N);
    ew_kernel<<<neb, 256, 0, stream>>>(a_src, a_dst, sorted, sortedd, ew, E);
    agg_kernel<<<nblk, 256, 0, stream>>>(h, a_src, a_dst, row_ptr, sorted, ew, b1, x2, N);
    // layer 2
    gemm_att_kernel<<<ggrid, 256, 0, stream>>>(x2, Wt2_hi, Wt2_lo, att_s2, att_d2,
                                               h, a_src, a_dst, N);
    ew_kernel<<<neb, 256, 0, stream>>>(a_src, a_dst, sorted, sortedd, ew, E);
    agg_kernel<<<nblk, 256, 0, stream>>>(h, a_src, a_dst, row_ptr, sorted, ew, b2, out, N);
}

// Round 8
// 450.205 us; speedup vs baseline: 1.1214x; 1.0188x over previous
//
#include <hip/hip_runtime.h>
#include <hip/hip_bf16.h>

#define N_NODES 50000
#define N_EDGES 800000
// HEADS=4, OUT_CH=64, F=256 hard-coded. All harness I/O float32.
// Internal H layout INTERLEAVED: H[node*256 + c*4 + h]  (c=channel 0..63, h=head 0..3)

typedef __attribute__((ext_vector_type(8))) short short8;   // 8 bf16 = 4 VGPRs (MFMA A/B frag)
typedef __attribute__((ext_vector_type(4))) float floatx4;  // MFMA C/D frag
typedef __attribute__((ext_vector_type(2))) uint uintx2;

__device__ __forceinline__ ushort f2bf(float f) {           // RNE f32->bf16 bits
    uint u = __float_as_uint(f);
    uint r = u + 0x7FFFu + ((u >> 16) & 1u);
    return (ushort)(r >> 16);
}
__device__ __forceinline__ float bfu2f(ushort h) {
    return __uint_as_float(((uint)h) << 16);
}
__device__ __forceinline__ float bflo(uint u) { return __uint_as_float(u << 16); }
__device__ __forceinline__ float bfhi(uint u) { return __uint_as_float(u & 0xffff0000u); }
__device__ __forceinline__ float lrelu(float e) { return e >= 0.f ? e : 0.2f * e; }

// ---------------- CSR build (dst-sorted incoming edge lists) ----------------
__global__ void deg_kernel(const int* __restrict__ dst, int* __restrict__ cnt, int E) {
    int i = blockIdx.x * blockDim.x + threadIdx.x;
    if (i < E) atomicAdd(&cnt[dst[i]], 1);
}

__global__ __launch_bounds__(256) void scan1_kernel(const int* __restrict__ cnt,
                                                    int* __restrict__ excl,
                                                    int* __restrict__ partial, int n) {
    __shared__ int sd[256];
    int tid = threadIdx.x;
    int i = blockIdx.x * 256 + tid;
    int v = (i < n) ? cnt[i] : 0;
    sd[tid] = v;
    __syncthreads();
    #pragma unroll
    for (int off = 1; off < 256; off <<= 1) {
        int t = (tid >= off) ? sd[tid - off] : 0;
        __syncthreads();
        sd[tid] += t;
        __syncthreads();
    }
    if (i < n) excl[i] = sd[tid] - v;
    if (tid == 255) partial[blockIdx.x] = sd[255];
}

__global__ __launch_bounds__(256) void scan2_kernel(int* __restrict__ partial, int nb) {
    __shared__ int sd[256];
    int tid = threadIdx.x;
    int v = (tid < nb) ? partial[tid] : 0;
    sd[tid] = v;
    __syncthreads();
    #pragma unroll
    for (int off = 1; off < 256; off <<= 1) {
        int t = (tid >= off) ? sd[tid - off] : 0;
        __syncthreads();
        sd[tid] += t;
        __syncthreads();
    }
    if (tid < nb) partial[tid] = sd[tid] - v;   // exclusive
}

__global__ __launch_bounds__(256) void scan3_kernel(const int* __restrict__ excl,
                                                    const int* __restrict__ partial,
                                                    int* __restrict__ row_ptr,
                                                    int* __restrict__ row_tmp, int n) {
    int i = blockIdx.x * 256 + threadIdx.x;
    if (i < n) {
        int v = excl[i] + partial[blockIdx.x];
        row_ptr[i] = v;
        row_tmp[i] = v;
    }
    if (i == 0) row_ptr[n] = N_EDGES;
}

__global__ void scatter_kernel(const int* __restrict__ src, const int* __restrict__ dst,
                               int* __restrict__ row_tmp, int* __restrict__ sorted_src,
                               int* __restrict__ sorted_dst, int E) {
    int i = blockIdx.x * blockDim.x + threadIdx.x;
    if (i < E) {
        int d = dst[i];
        int p = atomicAdd(&row_tmp[d], 1);
        sorted_src[p] = src[i];
        sorted_dst[p] = d;
    }
}

// ------ W prep: transpose + bf16 hi/lo split (+ unused fused att rows) ------
__global__ __launch_bounds__(320) void prep_w(const float* __restrict__ W1,
                                              const float* __restrict__ W2,
                                              const float* __restrict__ as1,
                                              const float* __restrict__ ad1,
                                              const float* __restrict__ as2,
                                              const float* __restrict__ ad2,
                                              ushort* __restrict__ Wt1_hi,
                                              ushort* __restrict__ Wt1_lo,
                                              ushort* __restrict__ Wt2_hi,
                                              ushort* __restrict__ Wt2_lo) {
    int t = threadIdx.x, k = blockIdx.x & 255;
    int l1 = (blockIdx.x < 256);
    const float* W = l1 ? W1 : W2;
    const float* as_ = l1 ? as1 : as2;
    const float* ad_ = l1 ? ad1 : ad2;
    ushort* Wh = l1 ? Wt1_hi : Wt2_hi;
    ushort* Wl = l1 ? Wt1_lo : Wt2_lo;
    if (t < 256) {
        float v = W[k * 256 + t];
        ushort hb = f2bf(v);
        Wh[t * 256 + k] = hb;
        Wl[t * 256 + k] = f2bf(v - bfu2f(hb));
    } else if (t < 264) {
        int j = t - 256;
        int h = j & 3;
        const float* vec = (j < 4) ? as_ : ad_;
        float acc = 0.f;
        for (int c = 0; c < 64; c++) acc += W[k * 256 + h * 64 + c] * vec[h * 64 + c];
        ushort hb = f2bf(acc);
        Wh[t * 256 + k] = hb;
        Wl[t * 256 + k] = f2bf(acc - bfu2f(hb));
    } else if (t < 272) {
        Wh[t * 256 + k] = 0;
        Wl[t * 256 + k] = 0;
    }
}

// ------- GEMM + fused attention logits, col-split, DBUF + RAW BARRIERS ------
// R2-proven tile/addressing (64 rows x 128 cols, ROWP=40, bf16x3 MFMA) with a
// restructured k-loop: LDS double-buffered, ONE raw s_barrier per k-step with
// lgkmcnt(0)-only drain (NOT __syncthreads -- hipcc lowers that with a full
// vmcnt(0) drain, which kills any load pipelining across barriers, m97).
// Schedule per step t: issue W(t+1) global loads -> convert A(t) -> issue
// A(t+2) loads (2-deep, legally in flight ACROSS the raw barrier) -> MFMAs on
// buf[t&1] -> ds_write W(t+1) to buf[~t&1] (auto-waits its loads; had the
// whole compute phase to land) -> lgkmcnt(0) (orders this wave's LDS reads
// AND writes) -> raw s_barrier. Iter t+1's writes hit the buffer read at t,
// ordered by that barrier. Barriers/step: 2 -> 1; staging latency overlapped.
__global__ __launch_bounds__(256) void gemm_att_kernel(const float* __restrict__ A,
                                                       const ushort* __restrict__ Wt_hi,
                                                       const ushort* __restrict__ Wt_lo,
                                                       const float* __restrict__ att_s,
                                                       const float* __restrict__ att_d,
                                                       ushort* __restrict__ H,
                                                       float* __restrict__ a_src,
                                                       float* __restrict__ a_dst, int M) {
    const int ROWP = 40;
    __shared__ ushort hi_s[2][128 * ROWP];   // 2 x 10 KB
    __shared__ ushort lo_s[2][128 * ROWP];   // 2 x 10 KB
    const int tid = threadIdx.x;
    const int wave = tid >> 6, lane = tid & 63;
    const int quad = lane >> 4, l16 = lane & 15;
    const int brow = blockIdx.x * 64;
    const int coff = blockIdx.y * 128;    // column offset (also Wt row offset)
    const int mrow = brow + wave * 16 + l16;
    const int mload = (mrow < M) ? mrow : (M - 1);

    floatx4 acc[8];
    #pragma unroll
    for (int t = 0; t < 8; t++) acc[t] = (floatx4){0.f, 0.f, 0.f, 0.f};

    // staging role: threads 0-127 stage hi, 128-255 stage lo; col = tid&127
    const int scol = tid & 127;
    const ushort* gW = ((tid < 128) ? Wt_hi : Wt_lo) + (size_t)(coff + scol) * 256;
    ushort* sB0 = ((tid < 128) ? &hi_s[0][0] : &lo_s[0][0]) + scol * ROWP;
    ushort* sB1 = ((tid < 128) ? &hi_s[1][0] : &lo_s[1][0]) + scol * ROWP;

    const float* ap = A + (size_t)mload * 256 + quad * 8;

    // prologue: W(0) -> regs -> buf0; A(0), A(1) -> regs
    short8 wreg[4];
    #pragma unroll
    for (int i = 0; i < 4; i++)
        wreg[i] = *reinterpret_cast<const short8*>(gW + i * 8);
    float4 af0[2], af1[2];
    af0[0] = *reinterpret_cast<const float4*>(ap);
    af1[0] = *reinterpret_cast<const float4*>(ap + 4);
    af0[1] = *reinterpret_cast<const float4*>(ap + 32);
    af1[1] = *reinterpret_cast<const float4*>(ap + 36);
    #pragma unroll
    for (int i = 0; i < 4; i++)
        *reinterpret_cast<short8*>(sB0 + i * 8) = wreg[i];
    asm volatile("s_waitcnt lgkmcnt(0)" ::: "memory");
    __builtin_amdgcn_s_barrier();

    #pragma unroll
    for (int t = 0; t < 8; t++) {
        const int cur = t & 1;
        if (t < 7) {                      // issue W(t+1): lands during this step
            #pragma unroll
            for (int i = 0; i < 4; i++)
                wreg[i] = *reinterpret_cast<const short8*>(gW + (t + 1) * 32 + i * 8);
        }
        // convert A(t) -> bf16 hi/lo
        float av[8] = {af0[cur].x, af0[cur].y, af0[cur].z, af0[cur].w,
                       af1[cur].x, af1[cur].y, af1[cur].z, af1[cur].w};
        short8 a_hi, a_lo;
        #pragma unroll
        for (int j = 0; j < 8; j++) {
            ushort hb = f2bf(av[j]);
            a_hi[j] = (short)hb;
            a_lo[j] = (short)f2bf(av[j] - bfu2f(hb));
        }
        if (t < 6) {                      // A(t+2): 2-deep, crosses one raw barrier
            af0[cur] = *reinterpret_cast<const float4*>(ap + (t + 2) * 32);
            af1[cur] = *reinterpret_cast<const float4*>(ap + (t + 2) * 32 + 4);
        }
        const ushort* rh = (cur == 0) ? &hi_s[0][0] : &hi_s[1][0];
        const ushort* rl = (cur == 0) ? &lo_s[0][0] : &lo_s[1][0];
        #pragma unroll
        for (int tt = 0; tt < 8; tt++) {
            int roff = (tt * 16 + l16) * ROWP + quad * 8;
            short8 b_hi = *reinterpret_cast<const short8*>(rh + roff);
            short8 b_lo = *reinterpret_cast<const short8*>(rl + roff);
            acc[tt] = __builtin_amdgcn_mfma_f32_16x16x32_bf16(a_hi, b_hi, acc[tt], 0, 0, 0);
            acc[tt] = __builtin_amdgcn_mfma_f32_16x16x32_bf16(a_hi, b_lo, acc[tt], 0, 0, 0);
            acc[tt] = __builtin_amdgcn_mfma_f32_16x16x32_bf16(a_lo, b_hi, acc[tt], 0, 0, 0);
        }
        if (t < 7) {                      // stage W(t+1) into the other buffer
            ushort* sBn = cur ? sB0 : sB1;
            #pragma unroll
            for (int i = 0; i < 4; i++)
                *reinterpret_cast<short8*>(sBn + i * 8) = wreg[i];
        }
        asm volatile("s_waitcnt lgkmcnt(0)" ::: "memory");
        __builtin_amdgcn_s_barrier();
    }
    // fused attention-logit partials: tiles 0-3 -> head coff/64, 4-7 -> +1
    const int hb = blockIdx.y * 2;
    float ps[2][4] = {}, pd[2][4] = {};
    #pragma unroll
    for (int t = 0; t < 8; t++) {
        int hh = t >> 2;
        float as_v = att_s[coff + t * 16 + l16];
        float ad_v = att_d[coff + t * 16 + l16];
        #pragma unroll
        for (int r = 0; r < 4; r++) {
            ps[hh][r] += acc[t][r] * as_v;
            pd[hh][r] += acc[t][r] * ad_v;
        }
    }
    #pragma unroll
    for (int off = 1; off < 16; off <<= 1) {
        #pragma unroll
        for (int hh = 0; hh < 2; hh++)
            #pragma unroll
            for (int r = 0; r < 4; r++) {
                ps[hh][r] += __shfl_xor(ps[hh][r], off, 64);
                pd[hh][r] += __shfl_xor(pd[hh][r], off, 64);
            }
    }
    if (l16 == 0) {
        #pragma unroll
        for (int r = 0; r < 4; r++) {
            int m = brow + wave * 16 + quad * 4 + r;
            if (m < M) {
                #pragma unroll
                for (int hh = 0; hh < 2; hh++) {
                    a_src[m * 4 + hb + hh] = ps[hh][r];
                    a_dst[m * 4 + hb + hh] = pd[hh][r];
                }
            }
        }
    }
    // store bf16 H, interleaved (c*4 + h), packed head-pairs: tiles t and t+4
    // share c = t*16 + l16 and hold heads hb, hb+1 -> one uint store.
    #pragma unroll
    for (int t = 0; t < 4; t++) {
        int c = t * 16 + l16;
        #pragma unroll
        for (int r = 0; r < 4; r++) {
            int m = brow + wave * 16 + quad * 4 + r;
            if (m < M) {
                uint pk = (uint)f2bf(acc[t][r]) | ((uint)f2bf(acc[t + 4][r]) << 16);
                *reinterpret_cast<uint*>(H + (size_t)m * 256 + c * 4 + hb) = pk;
            }
        }
    }
}

// ---------------- edge weights: w = exp(lrelu(a_src[s]+a_dst[d])) -----------
// No max-subtraction: logits bounded (|e| ~ O(10)), f32 exp safe; alpha = w/sum(w)
// is mathematically identical to the max-subtracted form.
__global__ __launch_bounds__(256) void ew_kernel(const float* __restrict__ a_src,
                                                 const float* __restrict__ a_dst,
                                                 const int* __restrict__ sorted_src,
                                                 const int* __restrict__ sorted_dst,
                                                 float* __restrict__ ew, int E) {
    int j = blockIdx.x * 256 + threadIdx.x;
    if (j >= E) return;
    int s = sorted_src[j], d = sorted_dst[j];
    float4 as_ = *reinterpret_cast<const float4*>(a_src + (size_t)s * 4);
    float4 ad_ = *reinterpret_cast<const float4*>(a_dst + (size_t)d * 4);
    float4 w;
    w.x = __expf(lrelu(as_.x + ad_.x));
    w.y = __expf(lrelu(as_.y + ad_.y));
    w.z = __expf(lrelu(as_.z + ad_.z));
    w.w = __expf(lrelu(as_.w + ad_.w));
    *reinterpret_cast<float4*>(ew + (size_t)j * 4) = w;
}

// ---------------- weighted gather, one wave per node ------------------------
// All 64 lanes on ONE edge: lane = channel c, uint2 = heads 0..3 bf16.
// Node index forced wave-uniform via readfirstlane so the per-edge metadata
// (sorted_src, ew) compiles to scalar loads; 8 H-row gathers in flight.
// Tail groups over-read: memory-safe because sorted/sortedd and ew/a_src are
// exactly contiguous in the workspace (garbage indices are still valid node
// ids in [0,N)); invalid weights are skipped under a uniform branch.
// NOTE: macro params named W_/V_ to avoid the preprocessor substituting the
// parameter name inside swizzle members (.w).
#define AGG_ACC(W_, V_)                                                     \
    do {                                                                    \
        a0 += (W_).x * bflo((V_).x); a1 += (W_).y * bfhi((V_).x);           \
        a2 += (W_).z * bflo((V_).y); a3 += (W_).w * bfhi((V_).y);           \
        dp0 += (W_).x; dp1 += (W_).y; dp2 += (W_).z; dp3 += (W_).w;         \
    } while (0)

__global__ __launch_bounds__(256) void agg_kernel(const ushort* __restrict__ H,
                                                  const float* __restrict__ a_src,
                                                  const float* __restrict__ a_dst,
                                                  const int* __restrict__ row_ptr,
                                                  const int* __restrict__ sorted_src,
                                                  const float* __restrict__ ew,
                                                  const float* __restrict__ bias,
                                                  float* __restrict__ out, int N) {
    const int lane = threadIdx.x & 63;
    const int i = __builtin_amdgcn_readfirstlane(blockIdx.x * 4 + (threadIdx.x >> 6));
    if (i >= N) return;
    const float4 asv = *reinterpret_cast<const float4*>(a_src + (size_t)i * 4);
    const float4 adv = *reinterpret_cast<const float4*>(a_dst + (size_t)i * 4);
    const float ws0 = __expf(lrelu(asv.x + adv.x)), ws1 = __expf(lrelu(asv.y + adv.y));
    const float ws2 = __expf(lrelu(asv.z + adv.z)), ws3 = __expf(lrelu(asv.w + adv.w));
    const int start = row_ptr[i], end = row_ptr[i + 1];

    float a0 = 0.f, a1 = 0.f, a2 = 0.f, a3 = 0.f;
    float dp0 = 0.f, dp1 = 0.f, dp2 = 0.f, dp3 = 0.f;
    const ushort* __restrict__ Hl = H + lane * 4;   // this lane's channel slice

    for (int j0 = start; j0 < end; j0 += 8) {
        int s[8];
        #pragma unroll
        for (int k = 0; k < 8; k++) s[k] = sorted_src[j0 + k];        // s_load_dwordx8
        floatx4 w[8];
        #pragma unroll
        for (int k = 0; k < 8; k++)                                   // 2x s_load_dwordx16
            w[k] = *reinterpret_cast<const floatx4*>(ew + (size_t)(j0 + k) * 4);
        uintx2 hv[8];
        #pragma unroll
        for (int k = 0; k < 8; k++)                                   // 8 gathers in flight
            hv[k] = *reinterpret_cast<const uintx2*>(Hl + (size_t)s[k] * 256);
        if (j0 + 8 <= end) {
            #pragma unroll
            for (int k = 0; k < 8; k++) AGG_ACC(w[k], hv[k]);
        } else {
            #pragma unroll
            for (int k = 0; k < 8; k++)
                if (j0 + k < end) AGG_ACC(w[k], hv[k]);               // uniform branch
        }
    }
    // self loop
    {
        uintx2 hv = *reinterpret_cast<const uintx2*>(Hl + (size_t)i * 256);
        a0 += ws0 * bflo(hv.x); a1 += ws1 * bfhi(hv.x);
        a2 += ws2 * bflo(hv.y); a3 += ws3 * bfhi(hv.y);
    }
    const float r0 = 1.f / (dp0 + ws0 + 1e-16f), r1 = 1.f / (dp1 + ws1 + 1e-16f);
    const float r2 = 1.f / (dp2 + ws2 + 1e-16f), r3 = 1.f / (dp3 + ws3 + 1e-16f);
    // out[i*256 + h*64 + c], c = lane; nontemporal: don't evict H from L2
    float* op = out + (size_t)i * 256 + lane;
    float v;
    v = a0 * r0 + bias[lane];        v = (v > 0.f) ? v : expm1f(v);
    __builtin_nontemporal_store(v, op);
    v = a1 * r1 + bias[64 + lane];   v = (v > 0.f) ? v : expm1f(v);
    __builtin_nontemporal_store(v, op + 64);
    v = a2 * r2 + bias[128 + lane];  v = (v > 0.f) ? v : expm1f(v);
    __builtin_nontemporal_store(v, op + 128);
    v = a3 * r3 + bias[192 + lane];  v = (v > 0.f) ? v : expm1f(v);
    __builtin_nontemporal_store(v, op + 192);
}

extern "C" void kernel_launch(void* const* d_in, const int* in_sizes, int n_in,
                              void* d_out, int out_size, void* d_ws, size_t ws_size,
                              hipStream_t stream) {
    const float* x      = (const float*)d_in[0];
    const int*   eidx   = (const int*)d_in[1];
    const float* W1     = (const float*)d_in[2];
    const float* att_s1 = (const float*)d_in[3];
    const float* att_d1 = (const float*)d_in[4];
    const float* b1     = (const float*)d_in[5];
    const float* W2     = (const float*)d_in[6];
    const float* att_s2 = (const float*)d_in[7];
    const float* att_d2 = (const float*)d_in[8];
    const float* b2     = (const float*)d_in[9];
    float* out = (float*)d_out;

    const int N = N_NODES, E = N_EDGES;
    char* ws = (char*)d_ws;
    size_t off = 0;
    auto alloc = [&](size_t bytes) -> void* {
        void* p = ws + off;
        off += (bytes + 255) & ~(size_t)255;
        return p;
    };
    // total ws ~ 48 MB (proven-good envelope: 57 MB)
    // NOTE: agg_kernel's tail over-read relies on (ew -> a_src) and
    // (sorted -> sortedd) being contiguous: E*16 and E*4 are 256-aligned.
    ushort* h       = (ushort*)alloc((size_t)N * 256 * sizeof(ushort));  // 25.6 MB
    float*  ew      = (float*) alloc((size_t)E * 4 * sizeof(float));     // 12.8 MB
    float*  a_src   = (float*) alloc((size_t)N * 4 * sizeof(float));
    float*  a_dst   = (float*) alloc((size_t)N * 4 * sizeof(float));
    int*    cnt     = (int*)   alloc((size_t)N * sizeof(int));
    int*    row_ptr = (int*)   alloc((size_t)(N + 1) * sizeof(int));
    int*    row_tmp = (int*)   alloc((size_t)N * sizeof(int));
    int*    sorted  = (int*)   alloc((size_t)E * sizeof(int));
    int*    sortedd = (int*)   alloc((size_t)E * sizeof(int));
    int*    excl    = (int*)   alloc((size_t)N * sizeof(int));
    int*    partial = (int*)   alloc(256 * sizeof(int));
    ushort* Wt1_hi  = (ushort*)alloc(272 * 256 * sizeof(ushort));   // 256 W^T + 8 att + 8 zero
    ushort* Wt1_lo  = (ushort*)alloc(272 * 256 * sizeof(ushort));
    ushort* Wt2_hi  = (ushort*)alloc(272 * 256 * sizeof(ushort));
    ushort* Wt2_lo  = (ushort*)alloc(272 * 256 * sizeof(ushort));
    float*  x2      = out;   // layer-1 f32 activations live in d_out, overwritten by layer 2
    (void)ws_size; (void)in_sizes; (void)n_in; (void)out_size;

    const int* e_src = eidx;
    const int* e_dst = eidx + E;
    const int nsb = (N + 255) / 256;   // 196 scan blocks
    const int neb = (E + 255) / 256;

    prep_w<<<512, 320, 0, stream>>>(W1, W2, att_s1, att_d1, att_s2, att_d2,
                                    Wt1_hi, Wt1_lo, Wt2_hi, Wt2_lo);
    hipMemsetAsync(cnt, 0, N * sizeof(int), stream);
    deg_kernel<<<neb, 256, 0, stream>>>(e_dst, cnt, E);
    scan1_kernel<<<nsb, 256, 0, stream>>>(cnt, excl, partial, N);
    scan2_kernel<<<1, 256, 0, stream>>>(partial, nsb);
    scan3_kernel<<<nsb, 256, 0, stream>>>(excl, partial, row_ptr, row_tmp, N);
    scatter_kernel<<<neb, 256, 0, stream>>>(e_src, e_dst, row_tmp, sorted, sortedd, E);

    dim3 ggrid((N + 63) / 64, 2);  // 782 x 2
    int nblk = (N + 3) / 4;        // 12500
    // layer 1
    gemm_att_kernel<<<ggrid, 256, 0, stream>>>(x, Wt1_hi, Wt1_lo, att_s1, att_d1,
                                               h, a_src, a_dst, N);
    ew_kernel<<<neb, 256, 0, stream>>>(a_src, a_dst, sorted, sortedd, ew, E);
    agg_kernel<<<nblk, 256, 0, stream>>>(h, a_src, a_dst, row_ptr, sorted, ew, b1, x2, N);
    // layer 2
    gemm_att_kernel<<<ggrid, 256, 0, stream>>>(x2, Wt2_hi, Wt2_lo, att_s2, att_d2,
                                               h, a_src, a_dst, N);
    ew_kernel<<<neb, 256, 0, stream>>>(a_src, a_dst, sorted, sortedd, ew, E);
    agg_kernel<<<nblk, 256, 0, stream>>>(h, a_src, a_dst, row_ptr, sorted, ew, b2, out, N);
}